// Round 6
// baseline (1230.876 us; speedup 1.0000x reference)
//
#include <hip/hip_runtime.h>
#include <cstdint>
#include <cstddef>

#define B_ 64
#define N_ 16384
#define C_ 10
#define D_ 8
#define E_ 16
#define NTB_ 4                    // n per chunk (one K-quad)
#define NCHK_ 4                   // chunks per block
#define NPB_ (NTB_ * NCHK_)       // 16 n per block
#define GRID_ (N_ / NPB_)         // 1024 blocks
#define SVOL_ (B_ * C_ * E_)      // 10240 floats
#define WCH_ (NTB_ * C_ * E_ * 4) // 2560 u32 per W chunk

typedef __attribute__((ext_vector_type(8))) short short8;
typedef __attribute__((ext_vector_type(4))) float f32x4;

__device__ __forceinline__ uint32_t f2bf(float f) {
  uint32_t u = __builtin_bit_cast(uint32_t, f);
  return (u + 0x7fffu + ((u >> 16) & 1u)) >> 16;   // RNE
}
__device__ __forceinline__ uint32_t pack2(float lo, float hi) {
  return f2bf(lo) | (f2bf(hi) << 16);
}

// ---------------------------------------------------------------------------
// One routing pass. Block = 16 n x all 64 b, 4 waves; wave wv owns b-tile
// b = wv*16 + (lane&15).
// ITER 0 (verified r5): K-quad full-K MFMA — lane-group kg holds n-sub kg:
//   A[row=e][k=8*kg+d] = W[n0+kg, c, d, e], B[k=8*kg+d][col=b] = x[b,n0+kg,d]
//   one MFMA per c sums 4 n's. No softmax.
// ITER 1 (verified r4): per-n MFMA with lanes<16 holding k=0..7, lanes>=16
//   zero frags; logits via in-register 4-dot + shfl_xor(16/32); softmax per
//   lane; FMA-accumulate into acc (u kept live, wf streamed per c).
// Register budget: acc[10]x4 + vf[10]x4 + u[10]x4 interleaved ~= 128 cap
// from __launch_bounds__(256,4) -> 4 waves/SIMD; LDS 36 KB -> 4 blocks/CU.
// ---------------------------------------------------------------------------
template <int ITER>
__global__ __launch_bounds__(256, 4) void accum_kernel(
    const float* __restrict__ x,     // [B][N][D]
    const float* __restrict__ W,     // [N][C][D][E]
    const float* __restrict__ vacc,  // [B][C][E]
    float* __restrict__ scopy,       // [ncopy][B][C][E]
    int ncopy)
{
  __shared__ uint32_t wbuf[2][WCH_];        // [n][c][e][d2]  2 x 10 KB
  __shared__ uint32_t xbuf[NPB_ * B_ * 4];  // [n][b][d2]     16 KB

  const int tid = threadIdx.x;
  const int lane = tid & 63;
  const int wv = tid >> 6;
  const int l15 = lane & 15;
  const int kg = lane >> 4;       // frag k-group / D e-group
  const int n0 = blockIdx.x * NPB_;
  const int b = wv * 16 + l15;

  const short8 kzero = (short8){0, 0, 0, 0, 0, 0, 0, 0};
  const f32x4 fzero = (f32x4){0.f, 0.f, 0.f, 0.f};

  f32x4 vf[C_];
  if (ITER) {
#pragma unroll
    for (int c = 0; c < C_; ++c)
      vf[c] = *(const f32x4*)&vacc[(b * C_ + c) * E_ + kg * 4];
  }

  f32x4 acc[C_];
#pragma unroll
  for (int c = 0; c < C_; ++c) acc[c] = fzero;

  // stage x for all 16 n (verified r5): xbuf[(nl*B + bb)*4 + d2], tid=bb*4+d2
#pragma unroll
  for (int nl = 0; nl < NPB_; ++nl) {
    int bb = tid >> 2, d2 = tid & 3;
    const float* p = x + ((size_t)bb * N_ + n0 + nl) * D_ + d2 * 2;
    xbuf[nl * 256 + tid] = pack2(p[0], p[1]);
  }

  auto stage_w = [&](int pb, int nbase) {   // verified r5
#pragma unroll
    for (int it = 0; it < 10; ++it) {
      int i = it * 256 + tid;          // 0..2559
      int n = i / 640, r = i - n * 640;
      int c = r >> 6, r2 = r & 63;
      int d2 = r2 >> 4, e = r2 & 15;
      const float* p = W + ((size_t)(nbase + n) * C_ + c) * 128 + d2 * 32 + e;
      wbuf[pb][((n * C_ + c) * E_ + e) * 4 + d2] = pack2(p[0], p[16]);
    }
  };

  stage_w(0, n0);
  __syncthreads();

  for (int ch = 0; ch < NCHK_; ++ch) {
    if (ch + 1 < NCHK_) stage_w((ch + 1) & 1, n0 + (ch + 1) * NTB_);
    const uint32_t* wb = wbuf[ch & 1];

    if (ITER == 0) {
      // K-quad: full-wave frags, one MFMA per c sums the 4 n's (verified r5)
      short8 xq = *(const short8*)&xbuf[((ch * NTB_ + kg) * B_ + b) * 4];
#pragma unroll
      for (int c = 0; c < C_; ++c) {
        short8 wfq = *(const short8*)&wb[((kg * C_ + c) * E_ + l15) * 4];
        acc[c] = __builtin_amdgcn_mfma_f32_16x16x32_bf16(wfq, xq, acc[c], 0, 0, 0);
      }
    } else {
      // per-n path (verified r4): lanes<16 hold k=0..7, others zero
      for (int nn = 0; nn < NTB_; ++nn) {
        short8 xf = kzero;
        if (lane < 16)
          xf = *(const short8*)&xbuf[((ch * NTB_ + nn) * B_ + wv * 16 + l15) * 4];
        f32x4 u[C_];
#pragma unroll
        for (int c = 0; c < C_; ++c) {
          short8 wf = kzero;
          if (lane < 16)
            wf = *(const short8*)&wb[((nn * C_ + c) * E_ + l15) * 4];
          u[c] = __builtin_amdgcn_mfma_f32_16x16x32_bf16(wf, xf, fzero, 0, 0, 0);
        }
        float ew[C_];
#pragma unroll
        for (int c = 0; c < C_; ++c) {
          float t = u[c][0] * vf[c][0] + u[c][1] * vf[c][1] +
                    u[c][2] * vf[c][2] + u[c][3] * vf[c][3];
          t += __shfl_xor(t, 16);
          t += __shfl_xor(t, 32);   // full e-sum, all lanes
          ew[c] = __expf(t);
        }
        // pairwise-tree sum of 10 exps
        float s01 = ew[0] + ew[1], s23 = ew[2] + ew[3], s45 = ew[4] + ew[5],
              s67 = ew[6] + ew[7], s89 = ew[8] + ew[9];
        float ssum = ((s01 + s23) + (s45 + s67)) + s89;
        float inv = __builtin_amdgcn_rcpf(ssum);
#pragma unroll
        for (int c = 0; c < C_; ++c) {
          float cw = ew[c] * inv;
          acc[c][0] = fmaf(cw, u[c][0], acc[c][0]);
          acc[c][1] = fmaf(cw, u[c][1], acc[c][1]);
          acc[c][2] = fmaf(cw, u[c][2], acc[c][2]);
          acc[c][3] = fmaf(cw, u[c][3], acc[c][3]);
        }
      }
    }
    __syncthreads();
  }

  // flush: thread owns s[b][c][kg*4..+3]
  const float scale = (ITER == 0) ? 0.1f : 1.0f;
  float* sc = scopy + (size_t)(blockIdx.x & (ncopy - 1)) * SVOL_;
#pragma unroll
  for (int c = 0; c < C_; ++c)
#pragma unroll
    for (int r = 0; r < 4; ++r)
      atomicAdd(&sc[(b * C_ + c) * E_ + kg * 4 + r], acc[c][r] * scale);
}

// ---------------------------------------------------------------------------
// Reduce striped s copies, apply squash. 16 consecutive lanes = one capsule.
// MODE 0: vacc = v (re-zero stripes)  MODE 1: vacc += v (re-zero)
// MODE 2: out = v (no re-zero; launch-start memset covers next replay)
// ---------------------------------------------------------------------------
template <int MODE>
__global__ __launch_bounds__(256) void squash_kernel(
    float* __restrict__ scopy, int ncopy,
    float* __restrict__ vacc, float* __restrict__ out)
{
  int t = blockIdx.x * 256 + threadIdx.x;  // 0..10239
  float sv = 0.f;
  for (int k = 0; k < ncopy; ++k) {
    sv += scopy[(size_t)k * SVOL_ + t];
    if (MODE != 2) scopy[(size_t)k * SVOL_ + t] = 0.f;
  }
  float sq = sv * sv;
  sq += __shfl_xor(sq, 1);
  sq += __shfl_xor(sq, 2);
  sq += __shfl_xor(sq, 4);
  sq += __shfl_xor(sq, 8);
  float scale = sq / (1.f + sq) * rsqrtf(sq + 1e-7f);
  float v = scale * sv;
  if (MODE == 0)      vacc[t] = v;
  else if (MODE == 1) vacc[t] += v;
  else                out[t] = v;
}

extern "C" void kernel_launch(void* const* d_in, const int* in_sizes, int n_in,
                              void* d_out, int out_size, void* d_ws, size_t ws_size,
                              hipStream_t stream)
{
  const float* x = (const float*)d_in[0];  // [64][16384][8]
  const float* W = (const float*)d_in[1];  // [16384][10][8][16]
  float* out = (float*)d_out;              // [64][10][16]

  int ncopy = 64;
  while (ncopy > 1 && (size_t)(ncopy + 1) * SVOL_ * sizeof(float) > ws_size)
    ncopy >>= 1;
  float* s_ws = (float*)d_ws;
  float* vacc = s_ws + (size_t)ncopy * SVOL_;
  const size_t s_bytes = (size_t)ncopy * SVOL_ * sizeof(float);

  // single memset per launch; squash<0>/<1> re-zero stripes between passes
  hipMemsetAsync(s_ws, 0, s_bytes, stream);

  // pass 0: uniform c=0.1 -> s0 -> v0
  accum_kernel<0><<<GRID_, 256, 0, stream>>>(x, W, vacc, s_ws, ncopy);
  squash_kernel<0><<<SVOL_ / 256, 256, 0, stream>>>(s_ws, ncopy, vacc, out);

  // pass 1: logits = u.v0 -> s1 -> v1; vacc = v0 + v1
  accum_kernel<1><<<GRID_, 256, 0, stream>>>(x, W, vacc, s_ws, ncopy);
  squash_kernel<1><<<SVOL_ / 256, 256, 0, stream>>>(s_ws, ncopy, vacc, out);

  // pass 2: logits = u.(v0+v1) -> v2 = output
  accum_kernel<1><<<GRID_, 256, 0, stream>>>(x, W, vacc, s_ws, ncopy);
  squash_kernel<2><<<SVOL_ / 256, 256, 0, stream>>>(s_ws, ncopy, vacc, out);
}

// Round 7
// 537.334 us; speedup vs baseline: 2.2907x; 2.2907x over previous
//
#include <hip/hip_runtime.h>
#include <cstdint>
#include <cstddef>

#define B_ 64
#define N_ 16384
#define C_ 10
#define D_ 8
#define E_ 16
#define NTB_ 4                    // n per chunk (one K-quad)
#define NCHK_ 4                   // chunks per block
#define NPB_ (NTB_ * NCHK_)       // 16 n per block
#define GRID_ (N_ / NPB_)         // 1024 blocks
#define SVOL_ (B_ * C_ * E_)      // 10240 floats
#define WCH_ (NTB_ * C_ * E_ * 4) // 2560 u32 per W chunk

typedef __attribute__((ext_vector_type(8))) short short8;
typedef __attribute__((ext_vector_type(4))) float f32x4;
typedef __attribute__((ext_vector_type(4))) uint32_t u32x4;

__device__ __forceinline__ uint32_t f2bf(float f) {
  uint32_t u = __builtin_bit_cast(uint32_t, f);
  return (u + 0x7fffu + ((u >> 16) & 1u)) >> 16;   // RNE
}
__device__ __forceinline__ uint32_t pack2(float lo, float hi) {
  return f2bf(lo) | (f2bf(hi) << 16);
}

// ---------------------------------------------------------------------------
// One routing pass. Block = 16 n x all 64 b, 4 waves; wave wv owns b-tile
// b = wv*16 + (lane&15); kg = lane>>4 doubles as (K-group, e-group, n-sub).
// ITER 0 (verified r5/r6): K-quad full-K MFMA, one MFMA per c sums 4 n.
// ITER 1 (new structure, verified pieces only):
//   Phase L: per n-sub nn: masked-B MFMA (r5) -> u (transient) -> dot with
//     vf (r4 D-layout) -> shfl_xor(16/32) -> softmax. Lane KEEPS only cw for
//     nn == its own kg (cwm[10] regs; logits are broadcast by the reduce).
//   Phase S: B-operand rebuilt as bf16(cwm[c] * x[b,n_kg,d]) in the exact r5
//     xq k-slot layout; full-K W-quad MFMA accumulates s for all 4 n at once:
//     acc[c] = mfma(wfq, cw-scaled-x, acc[c]).  u is never materialized.
// Register peak ~ vf(40)+acc(40)+cwm(10)+xf(8)+misc -> no spill at cap 256.
// ---------------------------------------------------------------------------
template <int ITER>
__global__ __launch_bounds__(256, 2) void accum_kernel(
    const float* __restrict__ x,     // [B][N][D]
    const float* __restrict__ W,     // [N][C][D][E]
    const float* __restrict__ vacc,  // [B][C][E]
    float* __restrict__ scopy,       // [ncopy][B][C][E]
    int ncopy)
{
  __shared__ uint32_t wbuf[2][WCH_];        // [n][c][e][d2]  2 x 10 KB
  __shared__ uint32_t xbuf[NPB_ * B_ * 4];  // [n][b][d2]     16 KB

  const int tid = threadIdx.x;
  const int lane = tid & 63;
  const int wv = tid >> 6;
  const int l15 = lane & 15;
  const int kg = lane >> 4;       // K-group / e-group / n-sub
  const int n0 = blockIdx.x * NPB_;
  const int b = wv * 16 + l15;

  const short8 kzero = (short8){0, 0, 0, 0, 0, 0, 0, 0};
  const f32x4 fzero = (f32x4){0.f, 0.f, 0.f, 0.f};

  f32x4 vf[C_];
  if (ITER) {
#pragma unroll
    for (int c = 0; c < C_; ++c)
      vf[c] = *(const f32x4*)&vacc[(b * C_ + c) * E_ + kg * 4];
  }

  f32x4 acc[C_];
#pragma unroll
  for (int c = 0; c < C_; ++c) acc[c] = fzero;

  // stage x for all 16 n (verified r5): xbuf[(nl*B + bb)*4 + d2], tid=bb*4+d2
#pragma unroll
  for (int nl = 0; nl < NPB_; ++nl) {
    int bb = tid >> 2, d2 = tid & 3;
    const float* p = x + ((size_t)bb * N_ + n0 + nl) * D_ + d2 * 2;
    xbuf[nl * 256 + tid] = pack2(p[0], p[1]);
  }

  auto stage_w = [&](int pb, int nbase) {   // verified r5
#pragma unroll
    for (int it = 0; it < 10; ++it) {
      int i = it * 256 + tid;          // 0..2559
      int n = i / 640, r = i - n * 640;
      int c = r >> 6, r2 = r & 63;
      int d2 = r2 >> 4, e = r2 & 15;
      const float* p = W + ((size_t)(nbase + n) * C_ + c) * 128 + d2 * 32 + e;
      wbuf[pb][((n * C_ + c) * E_ + e) * 4 + d2] = pack2(p[0], p[16]);
    }
  };

  stage_w(0, n0);
  __syncthreads();

  for (int ch = 0; ch < NCHK_; ++ch) {
    if (ch + 1 < NCHK_) stage_w((ch + 1) & 1, n0 + (ch + 1) * NTB_);
    const uint32_t* wb = wbuf[ch & 1];

    // this lane's x frag: k-group kg holds x[b, n0+ch*4+kg, 0..7] (r5)
    short8 xq = *(const short8*)&xbuf[((ch * NTB_ + kg) * B_ + b) * 4];

    if (ITER == 0) {
      // K-quad: one MFMA per c sums the 4 n's (verified r5/r6)
#pragma unroll
      for (int c = 0; c < C_; ++c) {
        short8 wfq = *(const short8*)&wb[((kg * C_ + c) * E_ + l15) * 4];
        acc[c] = __builtin_amdgcn_mfma_f32_16x16x32_bf16(wfq, xq, acc[c], 0, 0, 0);
      }
    } else {
      // ---- Phase L: logits + softmax; keep only own-kg couplings ----
      float cwm[C_];
#pragma unroll
      for (int nn = 0; nn < NTB_; ++nn) {
        const short8 xm = (kg == nn) ? xq : kzero;   // r5-verified B mask
        float ew[C_];
#pragma unroll
        for (int c = 0; c < C_; ++c) {
          short8 wfq = *(const short8*)&wb[((kg * C_ + c) * E_ + l15) * 4];
          f32x4 u = __builtin_amdgcn_mfma_f32_16x16x32_bf16(wfq, xm, fzero, 0, 0, 0);
          float t = u[0] * vf[c][0] + u[1] * vf[c][1] +
                    u[2] * vf[c][2] + u[3] * vf[c][3];
          t += __shfl_xor(t, 16);
          t += __shfl_xor(t, 32);   // full e-sum, broadcast to all lanes
          ew[c] = __expf(t);
        }
        float s01 = ew[0] + ew[1], s23 = ew[2] + ew[3], s45 = ew[4] + ew[5],
              s67 = ew[6] + ew[7], s89 = ew[8] + ew[9];
        float inv = __builtin_amdgcn_rcpf(((s01 + s23) + (s45 + s67)) + s89);
#pragma unroll
        for (int c = 0; c < C_; ++c)
          if (kg == nn) cwm[c] = ew[c] * inv;   // predicated keep (cndmask)
      }

      // ---- Phase S: acc[c] += sum_{n in quad} cw * u  via full-K MFMA ----
      float xf[D_];                  // unpack own x frag to f32 (once)
#pragma unroll
      for (int j = 0; j < D_; ++j) {
        uint32_t hw = (uint32_t)(uint16_t)xq[j];
        xf[j] = __builtin_bit_cast(float, hw << 16);
      }
#pragma unroll
      for (int c = 0; c < C_; ++c) {
        u32x4 bw;
        bw[0] = pack2(cwm[c] * xf[0], cwm[c] * xf[1]);
        bw[1] = pack2(cwm[c] * xf[2], cwm[c] * xf[3]);
        bw[2] = pack2(cwm[c] * xf[4], cwm[c] * xf[5]);
        bw[3] = pack2(cwm[c] * xf[6], cwm[c] * xf[7]);
        short8 bfrag = __builtin_bit_cast(short8, bw);
        short8 wfq = *(const short8*)&wb[((kg * C_ + c) * E_ + l15) * 4];
        acc[c] = __builtin_amdgcn_mfma_f32_16x16x32_bf16(wfq, bfrag, acc[c], 0, 0, 0);
      }
    }
    __syncthreads();
  }

  // flush: thread owns s[b][c][kg*4..+3]
  const float scale = (ITER == 0) ? 0.1f : 1.0f;
  float* sc = scopy + (size_t)(blockIdx.x & (ncopy - 1)) * SVOL_;
#pragma unroll
  for (int c = 0; c < C_; ++c)
#pragma unroll
    for (int r = 0; r < 4; ++r)
      atomicAdd(&sc[(b * C_ + c) * E_ + kg * 4 + r], acc[c][r] * scale);
}

// ---------------------------------------------------------------------------
// Reduce striped s copies, apply squash. 16 consecutive lanes = one capsule.
// MODE 0: vacc = v (re-zero stripes)  MODE 1: vacc += v (re-zero)
// MODE 2: out = v (no re-zero; launch-start memset covers next replay)
// ---------------------------------------------------------------------------
template <int MODE>
__global__ __launch_bounds__(256) void squash_kernel(
    float* __restrict__ scopy, int ncopy,
    float* __restrict__ vacc, float* __restrict__ out)
{
  int t = blockIdx.x * 256 + threadIdx.x;  // 0..10239
  float sv = 0.f;
  for (int k = 0; k < ncopy; ++k) {
    sv += scopy[(size_t)k * SVOL_ + t];
    if (MODE != 2) scopy[(size_t)k * SVOL_ + t] = 0.f;
  }
  float sq = sv * sv;
  sq += __shfl_xor(sq, 1);
  sq += __shfl_xor(sq, 2);
  sq += __shfl_xor(sq, 4);
  sq += __shfl_xor(sq, 8);
  float scale = sq / (1.f + sq) * rsqrtf(sq + 1e-7f);
  float v = scale * sv;
  if (MODE == 0)      vacc[t] = v;
  else if (MODE == 1) vacc[t] += v;
  else                out[t] = v;
}

extern "C" void kernel_launch(void* const* d_in, const int* in_sizes, int n_in,
                              void* d_out, int out_size, void* d_ws, size_t ws_size,
                              hipStream_t stream)
{
  const float* x = (const float*)d_in[0];  // [64][16384][8]
  const float* W = (const float*)d_in[1];  // [16384][10][8][16]
  float* out = (float*)d_out;              // [64][10][16]

  int ncopy = 64;
  while (ncopy > 1 && (size_t)(ncopy + 1) * SVOL_ * sizeof(float) > ws_size)
    ncopy >>= 1;
  float* s_ws = (float*)d_ws;
  float* vacc = s_ws + (size_t)ncopy * SVOL_;
  const size_t s_bytes = (size_t)ncopy * SVOL_ * sizeof(float);

  // single memset per launch; squash<0>/<1> re-zero stripes between passes
  hipMemsetAsync(s_ws, 0, s_bytes, stream);

  // pass 0: uniform c=0.1 -> s0 -> v0
  accum_kernel<0><<<GRID_, 256, 0, stream>>>(x, W, vacc, s_ws, ncopy);
  squash_kernel<0><<<SVOL_ / 256, 256, 0, stream>>>(s_ws, ncopy, vacc, out);

  // pass 1: logits = u.v0 -> s1 -> v1; vacc = v0 + v1
  accum_kernel<1><<<GRID_, 256, 0, stream>>>(x, W, vacc, s_ws, ncopy);
  squash_kernel<1><<<SVOL_ / 256, 256, 0, stream>>>(s_ws, ncopy, vacc, out);

  // pass 2: logits = u.(v0+v1) -> v2 = output
  accum_kernel<1><<<GRID_, 256, 0, stream>>>(x, W, vacc, s_ws, ncopy);
  squash_kernel<2><<<SVOL_ / 256, 256, 0, stream>>>(s_ws, ncopy, vacc, out);
}

// Round 8
// 203.663 us; speedup vs baseline: 6.0437x; 2.6383x over previous
//
#include <hip/hip_runtime.h>
#include <cstdint>
#include <cstddef>

#define B_ 64
#define N_ 16384
#define C_ 10
#define D_ 8
#define E_ 16
#define NTB_ 4                    // n per chunk (one K-quad)
#define NCHK_ 4                   // chunks per block
#define NPB_ (NTB_ * NCHK_)       // 16 n per block
#define GRID_ (N_ / NPB_)         // 1024 blocks
#define SVOL_ (B_ * C_ * E_)      // 10240 floats
#define WSTR_ (C_ * E_ * 4 + 4)   // padded u32 stride per n in wbuf (644)
#define NP2_ 16                   // second-level partial count

typedef __attribute__((ext_vector_type(8))) short short8;
typedef __attribute__((ext_vector_type(4))) float f32x4;
typedef __attribute__((ext_vector_type(4))) uint32_t u32x4;

__device__ __forceinline__ uint32_t f2bf(float f) {
  uint32_t u = __builtin_bit_cast(uint32_t, f);
  return (u + 0x7fffu + ((u >> 16) & 1u)) >> 16;   // RNE
}
__device__ __forceinline__ uint32_t pack2(float lo, float hi) {
  return f2bf(lo) | (f2bf(hi) << 16);
}

// ---------------------------------------------------------------------------
// One routing pass. Block = 16 n x all 64 b, 4 waves; wave wv owns b-tile
// b = wv*16 + (lane&15); kg = lane>>4 = (K-group, e-group, n-sub).
// ITER 0 (verified r5/r6/r7): K-quad full-K MFMA, one MFMA per c sums 4 n.
// ITER 1 (verified r7): Phase L (masked-B MFMA -> logit dot -> shfl_xor 16/32
//   -> softmax; lane keeps own-kg couplings cwm[10]) + Phase S (B rebuilt as
//   bf16(cw*x) in the r5 k-slot layout; full-K W-quad MFMA accumulates s).
// FLUSH 0: atomic stripes (r7 path, ws fallback).
// FLUSH 1: non-atomic per-block partial store (no global atomics at all).
// ---------------------------------------------------------------------------
template <int ITER, int FLUSH>
__global__ __launch_bounds__(256, 2) void accum_kernel(
    const float* __restrict__ x,     // [B][N][D]
    const float* __restrict__ W,     // [N][C][D][E]
    const float* __restrict__ vacc,  // [B][C][E]
    float* __restrict__ sout,        // FLUSH1: [GRID][B][C][E]; FLUSH0: stripes
    int ncopy)
{
  __shared__ __align__(16) uint32_t wbuf[2][NTB_ * WSTR_]; // 2 x 10.3 KB
  __shared__ __align__(16) uint32_t xbuf[NPB_ * B_ * 4];   // 16 KB (swizzled)

  const int tid = threadIdx.x;
  const int lane = tid & 63;
  const int wv = tid >> 6;
  const int l15 = lane & 15;
  const int kg = lane >> 4;       // K-group / e-group / n-sub
  const int n0 = blockIdx.x * NPB_;
  const int b = wv * 16 + l15;

  const short8 kzero = (short8){0, 0, 0, 0, 0, 0, 0, 0};
  const f32x4 fzero = (f32x4){0.f, 0.f, 0.f, 0.f};

  f32x4 vf[C_];
  if (ITER) {
#pragma unroll
    for (int c = 0; c < C_; ++c)
      vf[c] = *(const f32x4*)&vacc[(b * C_ + c) * E_ + kg * 4];
  }

  f32x4 acc[C_];
#pragma unroll
  for (int c = 0; c < C_; ++c) acc[c] = fzero;

  // stage x, coalesced: 8 its x 256 thr x f32x4 = 8192 floats = 64b x 16n x 8d.
  // LDS layout [n][b][d2] with XOR swizzle ^((n&7)<<2) on the u32 index
  // (write banks 2-way, b128 read banks 2-way).
#pragma unroll
  for (int it = 0; it < 8; ++it) {
    int gidx = it * 256 + tid;
    int bb = gidx >> 5, q = gidx & 31, nn2 = q >> 1, dh = q & 1;
    f32x4 v4 = *(const f32x4*)(x + (size_t)bb * (N_ * D_) +
                               (size_t)(n0 + nn2) * D_ + dh * 4);
    int base = (((nn2 * B_ + bb) * 4) ^ ((nn2 & 7) << 2)) + dh * 2;
    xbuf[base] = pack2(v4[0], v4[1]);
    xbuf[base + 1] = pack2(v4[2], v4[3]);
  }

  auto stage_w = [&](int pb, int nbase) {   // verified r5 (WSTR_ pad added)
#pragma unroll
    for (int it = 0; it < 10; ++it) {
      int i = it * 256 + tid;          // 0..2559
      int n = i / 640, r = i - n * 640;
      int c = r >> 6, r2 = r & 63;
      int d2 = r2 >> 4, e = r2 & 15;
      const float* p = W + ((size_t)(nbase + n) * C_ + c) * 128 + d2 * 32 + e;
      wbuf[pb][n * WSTR_ + (c * E_ + e) * 4 + d2] = pack2(p[0], p[16]);
    }
  };

  stage_w(0, n0);
  __syncthreads();

  for (int ch = 0; ch < NCHK_; ++ch) {
    if (ch + 1 < NCHK_) stage_w((ch + 1) & 1, n0 + (ch + 1) * NTB_);
    const uint32_t* wb = wbuf[ch & 1];

    // this lane's x frag: k-group kg holds x[b, n0+ch*4+kg, 0..7] (r5)
    const int nl = ch * NTB_ + kg;
    short8 xq = *(const short8*)&xbuf[((nl * B_ + b) * 4) ^ ((nl & 7) << 2)];

    if (ITER == 0) {
      // K-quad: one MFMA per c sums the 4 n's (verified r5/r6/r7)
#pragma unroll
      for (int c = 0; c < C_; ++c) {
        short8 wfq = *(const short8*)&wb[kg * WSTR_ + (c * E_ + l15) * 4];
        acc[c] = __builtin_amdgcn_mfma_f32_16x16x32_bf16(wfq, xq, acc[c], 0, 0, 0);
      }
    } else {
      // ---- Phase L: logits + softmax; keep only own-kg couplings ----
      float cwm[C_];
#pragma unroll
      for (int nn = 0; nn < NTB_; ++nn) {
        const short8 xm = (kg == nn) ? xq : kzero;   // r5-verified B mask
        float ew[C_];
#pragma unroll
        for (int c = 0; c < C_; ++c) {
          short8 wfq = *(const short8*)&wb[kg * WSTR_ + (c * E_ + l15) * 4];
          f32x4 u = __builtin_amdgcn_mfma_f32_16x16x32_bf16(wfq, xm, fzero, 0, 0, 0);
          float t = u[0] * vf[c][0] + u[1] * vf[c][1] +
                    u[2] * vf[c][2] + u[3] * vf[c][3];
          t += __shfl_xor(t, 16);
          t += __shfl_xor(t, 32);   // full e-sum, broadcast to all lanes
          ew[c] = __expf(t);
        }
        float s01 = ew[0] + ew[1], s23 = ew[2] + ew[3], s45 = ew[4] + ew[5],
              s67 = ew[6] + ew[7], s89 = ew[8] + ew[9];
        float inv = __builtin_amdgcn_rcpf(((s01 + s23) + (s45 + s67)) + s89);
#pragma unroll
        for (int c = 0; c < C_; ++c)
          if (kg == nn) cwm[c] = ew[c] * inv;   // predicated keep (cndmask)
      }

      // ---- Phase S: acc[c] += sum_{n in quad} cw * u  via full-K MFMA ----
      float xf[D_];                  // unpack own x frag to f32 (once)
#pragma unroll
      for (int j = 0; j < D_; ++j) {
        uint32_t hw = (uint32_t)(uint16_t)xq[j];
        xf[j] = __builtin_bit_cast(float, hw << 16);
      }
#pragma unroll
      for (int c = 0; c < C_; ++c) {
        u32x4 bw;
        bw[0] = pack2(cwm[c] * xf[0], cwm[c] * xf[1]);
        bw[1] = pack2(cwm[c] * xf[2], cwm[c] * xf[3]);
        bw[2] = pack2(cwm[c] * xf[4], cwm[c] * xf[5]);
        bw[3] = pack2(cwm[c] * xf[6], cwm[c] * xf[7]);
        short8 bfrag = __builtin_bit_cast(short8, bw);
        short8 wfq = *(const short8*)&wb[kg * WSTR_ + (c * E_ + l15) * 4];
        acc[c] = __builtin_amdgcn_mfma_f32_16x16x32_bf16(wfq, bfrag, acc[c], 0, 0, 0);
      }
    }
    __syncthreads();
  }

  // flush: thread owns s[b][c][kg*4..+3]
  const float scale = (ITER == 0) ? 0.1f : 1.0f;
  if (FLUSH == 1) {
    // non-atomic per-block partial (block fully dirties its own 40 KB slot)
    f32x4* sc = (f32x4*)(sout + (size_t)blockIdx.x * SVOL_);
#pragma unroll
    for (int c = 0; c < C_; ++c) {
      f32x4 v = acc[c];
      v[0] *= scale; v[1] *= scale; v[2] *= scale; v[3] *= scale;
      sc[(b * C_ + c) * 4 + kg] = v;
    }
  } else {
    float* sc = sout + (size_t)(blockIdx.x & (ncopy - 1)) * SVOL_;
#pragma unroll
    for (int c = 0; c < C_; ++c)
#pragma unroll
      for (int r = 0; r < 4; ++r)
        atomicAdd(&sc[(b * C_ + c) * E_ + kg * 4 + r], acc[c][r] * scale);
  }
}

// ---------------------------------------------------------------------------
// FLUSH1 stage A: fold 1024 block-partials -> 16. Block (j, seg):
// j = k-range [j*64,(j+1)*64), seg covers 256 of the 10240 elements.
// ---------------------------------------------------------------------------
__global__ __launch_bounds__(256) void reduce_kernel(
    const float* __restrict__ parts, float* __restrict__ out16)
{
  int j = blockIdx.x / (SVOL_ / 256);
  int seg = blockIdx.x % (SVOL_ / 256);
  int t = seg * 256 + threadIdx.x;
  float s = 0.f;
#pragma unroll 8
  for (int k = j * (GRID_ / NP2_); k < (j + 1) * (GRID_ / NP2_); ++k)
    s += parts[(size_t)k * SVOL_ + t];
  out16[(size_t)j * SVOL_ + t] = s;
}

// ---------------------------------------------------------------------------
// Reduce np partials, apply squash. 16 consecutive lanes = one capsule.
// MODE 0: vacc = v   MODE 1: vacc += v   MODE 2: out = v
// REZERO: re-zero stripes after reading (atomic-fallback path only).
// ---------------------------------------------------------------------------
template <int MODE, int REZERO>
__global__ __launch_bounds__(256) void squash_kernel(
    float* __restrict__ scopy, int np,
    float* __restrict__ vacc, float* __restrict__ out)
{
  int t = blockIdx.x * 256 + threadIdx.x;  // 0..10239
  float sv = 0.f;
  for (int k = 0; k < np; ++k) {
    sv += scopy[(size_t)k * SVOL_ + t];
    if (REZERO && MODE != 2) scopy[(size_t)k * SVOL_ + t] = 0.f;
  }
  float sq = sv * sv;
  sq += __shfl_xor(sq, 1);
  sq += __shfl_xor(sq, 2);
  sq += __shfl_xor(sq, 4);
  sq += __shfl_xor(sq, 8);
  float scale = sq / (1.f + sq) * rsqrtf(sq + 1e-7f);
  float v = scale * sv;
  if (MODE == 0)      vacc[t] = v;
  else if (MODE == 1) vacc[t] += v;
  else                out[t] = v;
}

extern "C" void kernel_launch(void* const* d_in, const int* in_sizes, int n_in,
                              void* d_out, int out_size, void* d_ws, size_t ws_size,
                              hipStream_t stream)
{
  const float* x = (const float*)d_in[0];  // [64][16384][8]
  const float* W = (const float*)d_in[1];  // [16384][10][8][16]
  float* out = (float*)d_out;              // [64][10][16]

  const size_t need1 = ((size_t)GRID_ + NP2_ + 1) * SVOL_ * sizeof(float);

  if (ws_size >= need1) {
    // ---- fast path: no global atomics anywhere ----
    float* parts = (float*)d_ws;                       // [1024][SVOL]
    float* out16 = parts + (size_t)GRID_ * SVOL_;      // [16][SVOL]
    float* vacc = out16 + (size_t)NP2_ * SVOL_;        // [SVOL]
    const int RB = NP2_ * (SVOL_ / 256);               // 640 reduce blocks

    accum_kernel<0, 1><<<GRID_, 256, 0, stream>>>(x, W, vacc, parts, 0);
    reduce_kernel<<<RB, 256, 0, stream>>>(parts, out16);
    squash_kernel<0, 0><<<SVOL_ / 256, 256, 0, stream>>>(out16, NP2_, vacc, out);

    accum_kernel<1, 1><<<GRID_, 256, 0, stream>>>(x, W, vacc, parts, 0);
    reduce_kernel<<<RB, 256, 0, stream>>>(parts, out16);
    squash_kernel<1, 0><<<SVOL_ / 256, 256, 0, stream>>>(out16, NP2_, vacc, out);

    accum_kernel<1, 1><<<GRID_, 256, 0, stream>>>(x, W, vacc, parts, 0);
    reduce_kernel<<<RB, 256, 0, stream>>>(parts, out16);
    squash_kernel<2, 0><<<SVOL_ / 256, 256, 0, stream>>>(out16, NP2_, vacc, out);
  } else {
    // ---- fallback: r7 atomic-stripe path ----
    int ncopy = 64;
    while (ncopy > 1 && (size_t)(ncopy + 1) * SVOL_ * sizeof(float) > ws_size)
      ncopy >>= 1;
    float* s_ws = (float*)d_ws;
    float* vacc = s_ws + (size_t)ncopy * SVOL_;
    const size_t s_bytes = (size_t)ncopy * SVOL_ * sizeof(float);

    hipMemsetAsync(s_ws, 0, s_bytes, stream);

    accum_kernel<0, 0><<<GRID_, 256, 0, stream>>>(x, W, vacc, s_ws, ncopy);
    squash_kernel<0, 1><<<SVOL_ / 256, 256, 0, stream>>>(s_ws, ncopy, vacc, out);

    accum_kernel<1, 0><<<GRID_, 256, 0, stream>>>(x, W, vacc, s_ws, ncopy);
    squash_kernel<1, 1><<<SVOL_ / 256, 256, 0, stream>>>(s_ws, ncopy, vacc, out);

    accum_kernel<1, 0><<<GRID_, 256, 0, stream>>>(x, W, vacc, s_ws, ncopy);
    squash_kernel<2, 1><<<SVOL_ / 256, 256, 0, stream>>>(s_ws, ncopy, vacc, out);
  }
}

// Round 9
// 158.776 us; speedup vs baseline: 7.7523x; 1.2827x over previous
//
#include <hip/hip_runtime.h>
#include <cstdint>
#include <cstddef>

#define B_ 64
#define N_ 16384
#define C_ 10
#define D_ 8
#define E_ 16
#define NTB_ 4                    // n per chunk (one K-quad)
#define NCHK_ 4                   // chunks per block
#define NPB_ (NTB_ * NCHK_)       // 16 n per block
#define GRID_ (N_ / NPB_)         // 1024 blocks
#define SVOL_ (B_ * C_ * E_)      // 10240 floats
#define NP2_ 16                   // second-level partial count
#define WNU_ 640                  // u32 per n in Wb / wbuf (10c*16e*4d2)

typedef __attribute__((ext_vector_type(8))) short short8;
typedef __attribute__((ext_vector_type(4))) float f32x4;
typedef __attribute__((ext_vector_type(4))) uint32_t u32x4;

// single-instruction f32 pair -> packed bf16 (RNE), lo in [15:0]
__device__ __forceinline__ uint32_t pack2(float lo, float hi) {
  uint32_t r;
  asm("v_cvt_pk_bf16_f32 %0, %1, %2" : "=v"(r) : "v"(lo), "v"(hi));
  return r;
}

// async global->LDS, 16 B per lane; g is per-lane, l wave-uniform
__device__ __forceinline__ void gload16(const uint32_t* g, uint32_t* l) {
  __builtin_amdgcn_global_load_lds(
      (const __attribute__((address_space(1))) uint32_t*)g,
      (__attribute__((address_space(3))) uint32_t*)l, 16, 0, 0);
}

// ---------------------------------------------------------------------------
// Pre-conversion: W f32 [N][C][D][E] -> Wb u32 [N][WNU_] in exact wbuf frag
// order (index (c*16+e)*4+d2, d-pairs packed bf16). One u32x4 per thread.
// ---------------------------------------------------------------------------
__global__ __launch_bounds__(256) void convert_w_kernel(
    const float* __restrict__ W, uint32_t* __restrict__ Wb)
{
  int i4 = blockIdx.x * 256 + threadIdx.x;      // 0 .. N_*160-1
  int n = i4 / 160, r4 = i4 - n * 160;          // r4 = c*16+e
  int c = r4 >> 4, e = r4 & 15;
  const float* src = W + (size_t)(n * C_ + c) * 128 + e;  // d stride = 16
  u32x4 v;
  v[0] = pack2(src[0],  src[16]);
  v[1] = pack2(src[32], src[48]);
  v[2] = pack2(src[64], src[80]);
  v[3] = pack2(src[96], src[112]);
  *(u32x4*)(Wb + (size_t)n * WNU_ + r4 * 4) = v;
}

// x f32 [B][N][D] -> xc u32 [N][B][4] (bf16 d-pairs)
__global__ __launch_bounds__(256) void convert_x_kernel(
    const float* __restrict__ x, uint32_t* __restrict__ xc)
{
  int gi = blockIdx.x * 256 + threadIdx.x;      // 0 .. N_*B_-1
  int b = gi & 63, n = gi >> 6;
  const float* src = x + ((size_t)b * N_ + n) * D_;
  f32x4 lo = *(const f32x4*)src, hi = *(const f32x4*)(src + 4);
  u32x4 v;
  v[0] = pack2(lo[0], lo[1]);
  v[1] = pack2(lo[2], lo[3]);
  v[2] = pack2(hi[0], hi[1]);
  v[3] = pack2(hi[2], hi[3]);
  *(u32x4*)(xc + (size_t)gi * 4) = v;           // gi = n*64+b
}

// ---------------------------------------------------------------------------
// One routing pass. Block = 16 n x all 64 b, 4 waves; wave wv owns b-tile
// b = wv*16 + (lane&15); kg = lane>>4 = (K-group, e-group, n-sub).
// ITER 0 (verified r5-r8): K-quad full-K MFMA, one MFMA per c sums 4 n.
// ITER 1: phase L c-outer: per c one wfq load, 4 masked-B MFMAs (r5 mask),
//   per-lane e-dot, then 4x4 butterfly transpose-reduce over kg (xor16/xor32)
//   so each lane holds the logit for its OWN n-sub -> 1 exp per c, per-lane
//   softmax. Phase S (verified r7/r8): B rebuilt as bf16(cw*x) in the r5
//   k-slot layout; full-K W-quad MFMA accumulates s for all 4 n at once.
// PRE 1: stage from pre-converted Wb/xc via global_load_lds (no staging VALU).
// PRE 0: stage from f32 W/x with cvt_pk packing (r8 pattern).
// FLUSH 1: non-atomic per-block partial store.  FLUSH 0: atomic stripes.
// ---------------------------------------------------------------------------
template <int ITER, int PRE, int FLUSH>
__global__ __launch_bounds__(256, 2) void accum_kernel(
    const float* __restrict__ x, const float* __restrict__ W,
    const uint32_t* __restrict__ Wb, const uint32_t* __restrict__ xc,
    const float* __restrict__ vacc, float* __restrict__ sout, int ncopy)
{
  __shared__ __align__(16) uint32_t wbuf[2][NTB_ * WNU_];  // 2 x 10 KB
  __shared__ __align__(16) uint32_t xbuf[NPB_ * B_ * 4];   // 16 KB

  const int tid = threadIdx.x;
  const int lane = tid & 63;
  const int wv = tid >> 6;
  const int l15 = lane & 15;
  const int kg = lane >> 4;       // K-group / e-group / n-sub
  const int n0 = blockIdx.x * NPB_;
  const int b = wv * 16 + l15;

  const short8 kzero = (short8){0, 0, 0, 0, 0, 0, 0, 0};
  const f32x4 fzero = (f32x4){0.f, 0.f, 0.f, 0.f};

  f32x4 vf[C_];
  if (ITER) {
#pragma unroll
    for (int c = 0; c < C_; ++c)
      vf[c] = *(const f32x4*)&vacc[(b * C_ + c) * E_ + kg * 4];
  }

  f32x4 acc[C_];
#pragma unroll
  for (int c = 0; c < C_; ++c) acc[c] = fzero;

  // ---- stage x for all 16 n ----
  if (PRE) {
    const uint32_t* src = xc + (size_t)n0 * 256;   // 16 units of 1 KB
#pragma unroll
    for (int j = 0; j < 4; ++j) {
      int u = wv * 4 + j;
      gload16(src + u * 256 + lane * 4, &xbuf[u * 256]);
    }
  } else {
#pragma unroll
    for (int it = 0; it < 8; ++it) {
      int gidx = it * 256 + tid;
      int bb = gidx >> 5, q = gidx & 31, nn2 = q >> 1, dh = q & 1;
      f32x4 v4 = *(const f32x4*)(x + (size_t)bb * (N_ * D_) +
                                 (size_t)(n0 + nn2) * D_ + dh * 4);
      int base = (nn2 * B_ + bb) * 4 + dh * 2;
      xbuf[base] = pack2(v4[0], v4[1]);
      xbuf[base + 1] = pack2(v4[2], v4[3]);
    }
  }

  auto stage_w = [&](int pb, int nbase) {
    if (PRE) {
      const uint32_t* src = Wb + (size_t)nbase * WNU_;  // 10 units of 1 KB
#pragma unroll
      for (int k = 0; k < 3; ++k) {
        int u = wv + 4 * k;
        if (u < 10) gload16(src + u * 256 + lane * 4, &wbuf[pb][u * 256]);
      }
    } else {
#pragma unroll
      for (int it = 0; it < 10; ++it) {
        int i = it * 256 + tid;
        int n = i / 640, r = i - n * 640;
        int c = r >> 6, r2 = r & 63;
        int d2 = r2 >> 4, e = r2 & 15;
        const float* p = W + ((size_t)(nbase + n) * C_ + c) * 128 + d2 * 32 + e;
        wbuf[pb][n * WNU_ + (c * E_ + e) * 4 + d2] = pack2(p[0], p[16]);
      }
    }
  };

  stage_w(0, n0);
  __syncthreads();

  for (int ch = 0; ch < NCHK_; ++ch) {
    if (ch + 1 < NCHK_) stage_w((ch + 1) & 1, n0 + (ch + 1) * NTB_);
    const uint32_t* wb = wbuf[ch & 1];

    // this lane's x frag: k-group kg holds x[b, n0+ch*4+kg, 0..7] (r5)
    const int nl = ch * NTB_ + kg;
    short8 xq = *(const short8*)&xbuf[(nl * B_ + b) * 4];

    if (ITER == 0) {
      // K-quad: one MFMA per c sums the 4 n's (verified r5-r8)
#pragma unroll
      for (int c = 0; c < C_; ++c) {
        short8 wfq = *(const short8*)&wb[kg * WNU_ + (c * E_ + l15) * 4];
        acc[c] = __builtin_amdgcn_mfma_f32_16x16x32_bf16(wfq, xq, acc[c], 0, 0, 0);
      }
    } else {
      // masked B copies, one per n-sub (hoisted across c)
      short8 xm0 = (kg == 0) ? xq : kzero;
      short8 xm1 = (kg == 1) ? xq : kzero;
      short8 xm2 = (kg == 2) ? xq : kzero;
      short8 xm3 = (kg == 3) ? xq : kzero;
      const bool bb0 = (kg & 1) != 0;
      const bool bb1 = (kg & 2) != 0;

      // ---- Phase L: per c, 4 MFMAs + butterfly transpose-reduce ----
      float ew[C_];
#pragma unroll
      for (int c = 0; c < C_; ++c) {
        short8 wfq = *(const short8*)&wb[kg * WNU_ + (c * E_ + l15) * 4];
        f32x4 u0 = __builtin_amdgcn_mfma_f32_16x16x32_bf16(wfq, xm0, fzero, 0, 0, 0);
        f32x4 u1 = __builtin_amdgcn_mfma_f32_16x16x32_bf16(wfq, xm1, fzero, 0, 0, 0);
        f32x4 u2 = __builtin_amdgcn_mfma_f32_16x16x32_bf16(wfq, xm2, fzero, 0, 0, 0);
        f32x4 u3 = __builtin_amdgcn_mfma_f32_16x16x32_bf16(wfq, xm3, fzero, 0, 0, 0);
        f32x4 v = vf[c];
        float t0 = u0[0] * v[0] + u0[1] * v[1] + u0[2] * v[2] + u0[3] * v[3];
        float t1 = u1[0] * v[0] + u1[1] * v[1] + u1[2] * v[2] + u1[3] * v[3];
        float t2 = u2[0] * v[0] + u2[1] * v[1] + u2[2] * v[2] + u2[3] * v[3];
        float t3 = u3[0] * v[0] + u3[1] * v[1] + u3[2] * v[2] + u3[3] * v[3];
        // stage 1 (xor 16, kg bit0): keep t[bit0], send t[bit0^1]
        float keep_lo = bb0 ? t1 : t0, send_lo = bb0 ? t0 : t1;
        float keep_hi = bb0 ? t3 : t2, send_hi = bb0 ? t2 : t3;
        float ulo = keep_lo + __shfl_xor(send_lo, 16);
        float uhi = keep_hi + __shfl_xor(send_hi, 16);
        // stage 2 (xor 32, kg bit1): out m = kg
        float keep2 = bb1 ? uhi : ulo, send2 = bb1 ? ulo : uhi;
        float logit = keep2 + __shfl_xor(send2, 32);
        ew[c] = __expf(logit);   // logit for (b, n = n0+ch*4+kg, c)
      }
      float s01 = ew[0] + ew[1], s23 = ew[2] + ew[3], s45 = ew[4] + ew[5],
            s67 = ew[6] + ew[7], s89 = ew[8] + ew[9];
      float inv = __builtin_amdgcn_rcpf(((s01 + s23) + (s45 + s67)) + s89);

      // ---- Phase S: B rebuilt as bf16(cw*x); full-K MFMA accumulates ----
      float xf[D_];
#pragma unroll
      for (int j = 0; j < D_; ++j) {
        uint32_t hw = (uint32_t)(uint16_t)xq[j];
        xf[j] = __builtin_bit_cast(float, hw << 16);
      }
#pragma unroll
      for (int c = 0; c < C_; ++c) {
        float cw = ew[c] * inv;
        u32x4 bw;
        bw[0] = pack2(cw * xf[0], cw * xf[1]);
        bw[1] = pack2(cw * xf[2], cw * xf[3]);
        bw[2] = pack2(cw * xf[4], cw * xf[5]);
        bw[3] = pack2(cw * xf[6], cw * xf[7]);
        short8 bfrag = __builtin_bit_cast(short8, bw);
        short8 wfq = *(const short8*)&wb[kg * WNU_ + (c * E_ + l15) * 4];
        acc[c] = __builtin_amdgcn_mfma_f32_16x16x32_bf16(wfq, bfrag, acc[c], 0, 0, 0);
      }
    }
    __syncthreads();
  }

  // flush: thread owns s[b][c][kg*4..+3]
  const float scale = (ITER == 0) ? 0.1f : 1.0f;
  if (FLUSH == 1) {
    f32x4* sc = (f32x4*)(sout + (size_t)blockIdx.x * SVOL_);
#pragma unroll
    for (int c = 0; c < C_; ++c) {
      f32x4 v = acc[c];
      v[0] *= scale; v[1] *= scale; v[2] *= scale; v[3] *= scale;
      sc[(b * C_ + c) * 4 + kg] = v;
    }
  } else {
    float* sc = sout + (size_t)(blockIdx.x & (ncopy - 1)) * SVOL_;
#pragma unroll
    for (int c = 0; c < C_; ++c)
#pragma unroll
      for (int r = 0; r < 4; ++r)
        atomicAdd(&sc[(b * C_ + c) * E_ + kg * 4 + r], acc[c][r] * scale);
  }
}

// ---------------------------------------------------------------------------
// Fold 1024 block-partials -> 16 (verified r8).
// ---------------------------------------------------------------------------
__global__ __launch_bounds__(256) void reduce_kernel(
    const float* __restrict__ parts, float* __restrict__ out16)
{
  int j = blockIdx.x / (SVOL_ / 256);
  int seg = blockIdx.x % (SVOL_ / 256);
  int t = seg * 256 + threadIdx.x;
  float s = 0.f;
#pragma unroll 8
  for (int k = j * (GRID_ / NP2_); k < (j + 1) * (GRID_ / NP2_); ++k)
    s += parts[(size_t)k * SVOL_ + t];
  out16[(size_t)j * SVOL_ + t] = s;
}

// ---------------------------------------------------------------------------
// Reduce np partials, apply squash (verified r8).
// MODE 0: vacc = v   MODE 1: vacc += v   MODE 2: out = v
// ---------------------------------------------------------------------------
template <int MODE, int REZERO>
__global__ __launch_bounds__(256) void squash_kernel(
    float* __restrict__ scopy, int np,
    float* __restrict__ vacc, float* __restrict__ out)
{
  int t = blockIdx.x * 256 + threadIdx.x;  // 0..10239
  float sv = 0.f;
  for (int k = 0; k < np; ++k) {
    sv += scopy[(size_t)k * SVOL_ + t];
    if (REZERO && MODE != 2) scopy[(size_t)k * SVOL_ + t] = 0.f;
  }
  float sq = sv * sv;
  sq += __shfl_xor(sq, 1);
  sq += __shfl_xor(sq, 2);
  sq += __shfl_xor(sq, 4);
  sq += __shfl_xor(sq, 8);
  float scale = sq / (1.f + sq) * rsqrtf(sq + 1e-7f);
  float v = scale * sv;
  if (MODE == 0)      vacc[t] = v;
  else if (MODE == 1) vacc[t] += v;
  else                out[t] = v;
}

extern "C" void kernel_launch(void* const* d_in, const int* in_sizes, int n_in,
                              void* d_out, int out_size, void* d_ws, size_t ws_size,
                              hipStream_t stream)
{
  const float* x = (const float*)d_in[0];  // [64][16384][8]
  const float* W = (const float*)d_in[1];  // [16384][10][8][16]
  float* out = (float*)d_out;              // [64][10][16]

  const size_t WB_SZ = (size_t)N_ * WNU_ * 4;            // 41.9 MB
  const size_t XC_SZ = (size_t)N_ * B_ * 4 * 4;          // 16.8 MB
  const size_t PARTS_SZ = (size_t)GRID_ * SVOL_ * 4;     // 41.9 MB
  const size_t TAIL_SZ = (size_t)(NP2_ + 1) * SVOL_ * 4; // 0.7 MB
  const int RB = NP2_ * (SVOL_ / 256);                   // 640

  if (ws_size >= WB_SZ + XC_SZ + PARTS_SZ + TAIL_SZ) {
    // ---- tier A: pre-converted bf16 W/x + global_load_lds staging ----
    uint32_t* Wb = (uint32_t*)d_ws;
    uint32_t* xcv = (uint32_t*)((char*)d_ws + WB_SZ);
    float* parts = (float*)((char*)d_ws + WB_SZ + XC_SZ);
    float* out16 = parts + (size_t)GRID_ * SVOL_;
    float* vacc = out16 + (size_t)NP2_ * SVOL_;

    convert_w_kernel<<<N_ * 160 / 256, 256, 0, stream>>>(W, Wb);
    convert_x_kernel<<<N_ * B_ / 256, 256, 0, stream>>>(x, xcv);

    accum_kernel<0, 1, 1><<<GRID_, 256, 0, stream>>>(x, W, Wb, xcv, vacc, parts, 0);
    reduce_kernel<<<RB, 256, 0, stream>>>(parts, out16);
    squash_kernel<0, 0><<<SVOL_ / 256, 256, 0, stream>>>(out16, NP2_, vacc, out);

    accum_kernel<1, 1, 1><<<GRID_, 256, 0, stream>>>(x, W, Wb, xcv, vacc, parts, 0);
    reduce_kernel<<<RB, 256, 0, stream>>>(parts, out16);
    squash_kernel<1, 0><<<SVOL_ / 256, 256, 0, stream>>>(out16, NP2_, vacc, out);

    accum_kernel<1, 1, 1><<<GRID_, 256, 0, stream>>>(x, W, Wb, xcv, vacc, parts, 0);
    reduce_kernel<<<RB, 256, 0, stream>>>(parts, out16);
    squash_kernel<2, 0><<<SVOL_ / 256, 256, 0, stream>>>(out16, NP2_, vacc, out);
  } else if (ws_size >= PARTS_SZ + TAIL_SZ) {
    // ---- tier B: f32 staging (r8), non-atomic flush ----
    float* parts = (float*)d_ws;
    float* out16 = parts + (size_t)GRID_ * SVOL_;
    float* vacc = out16 + (size_t)NP2_ * SVOL_;

    accum_kernel<0, 0, 1><<<GRID_, 256, 0, stream>>>(x, W, nullptr, nullptr, vacc, parts, 0);
    reduce_kernel<<<RB, 256, 0, stream>>>(parts, out16);
    squash_kernel<0, 0><<<SVOL_ / 256, 256, 0, stream>>>(out16, NP2_, vacc, out);

    accum_kernel<1, 0, 1><<<GRID_, 256, 0, stream>>>(x, W, nullptr, nullptr, vacc, parts, 0);
    reduce_kernel<<<RB, 256, 0, stream>>>(parts, out16);
    squash_kernel<1, 0><<<SVOL_ / 256, 256, 0, stream>>>(out16, NP2_, vacc, out);

    accum_kernel<1, 0, 1><<<GRID_, 256, 0, stream>>>(x, W, nullptr, nullptr, vacc, parts, 0);
    reduce_kernel<<<RB, 256, 0, stream>>>(parts, out16);
    squash_kernel<2, 0><<<SVOL_ / 256, 256, 0, stream>>>(out16, NP2_, vacc, out);
  } else {
    // ---- tier C: atomic stripes (r7/r8 fallback) ----
    int ncopy = 64;
    while (ncopy > 1 && (size_t)(ncopy + 1) * SVOL_ * 4 > ws_size) ncopy >>= 1;
    float* s_ws = (float*)d_ws;
    float* vacc = s_ws + (size_t)ncopy * SVOL_;
    hipMemsetAsync(s_ws, 0, (size_t)ncopy * SVOL_ * 4, stream);

    accum_kernel<0, 0, 0><<<GRID_, 256, 0, stream>>>(x, W, nullptr, nullptr, vacc, s_ws, ncopy);
    squash_kernel<0, 1><<<SVOL_ / 256, 256, 0, stream>>>(s_ws, ncopy, vacc, out);

    accum_kernel<1, 0, 0><<<GRID_, 256, 0, stream>>>(x, W, nullptr, nullptr, vacc, s_ws, ncopy);
    squash_kernel<1, 1><<<SVOL_ / 256, 256, 0, stream>>>(s_ws, ncopy, vacc, out);

    accum_kernel<1, 0, 0><<<GRID_, 256, 0, stream>>>(x, W, nullptr, nullptr, vacc, s_ws, ncopy);
    squash_kernel<2, 1><<<SVOL_ / 256, 256, 0, stream>>>(s_ws, ncopy, vacc, out);
  }
}